// Round 13
// baseline (371.360 us; speedup 1.0000x reference)
//
#include <hip/hip_runtime.h>
#include <math.h>

#define BN 4
#define CC 32
#define HH 64
#define WW 64
#define DD 288          // C*K*K
#define EE 144
#define NTOK 4096
#define SCALE_F 0.2357022603955158f           // 18^-0.5
#define QSCALE  0.3401074286f                 // SCALE_F * log2(e)
#define QST 192         // qT row stride: 8 heads * 24 (Q only)
#define KST 32          // kP row stride: 24 real + 8 zero pad (64B rows)
#define MQKV 576        // padded QKV GEMM M: 192 Q + 192 K + 144 V + 48 zero pad (6 x 96)

typedef __bf16 bf16x8 __attribute__((ext_vector_type(8)));
typedef float floatx4 __attribute__((ext_vector_type(4)));
typedef unsigned short u16x8 __attribute__((ext_vector_type(8)));

__device__ __forceinline__ unsigned short f2bf(float x) {
    unsigned int u = __float_as_uint(x);
    u += 0x7fffu + ((u >> 16) & 1u);          // RNE
    return (unsigned short)(u >> 16);
}
__device__ __forceinline__ float bf2f(unsigned short s) {
    return __uint_as_float(((unsigned int)s) << 16);
}
// pack hi16(a), hi16(b) -> (b_hi<<16)|a_hi  — single v_perm_b32
__device__ __forceinline__ unsigned int pack_bf_trunc(float a, float b) {
    return __builtin_amdgcn_perm(__float_as_uint(b), __float_as_uint(a), 0x07060302u);
}
// gfx950 cross-lane row swaps (both operands read+written)
__device__ __forceinline__ void plswap32(unsigned int& a, unsigned int& b) {
    asm("v_permlane32_swap_b32 %0, %1" : "+v"(a), "+v"(b));
}
__device__ __forceinline__ void plswap16(unsigned int& a, unsigned int& b) {
    asm("v_permlane16_swap_b32 %0, %1" : "+v"(a), "+v"(b));
}
// bare v_exp_f32 (2^x) — OCML exp2f carries range/denorm fixup VALU (R8: -14 us/dispatch)
__device__ __forceinline__ float fexp2(float x) {
    return __builtin_amdgcn_exp2f(x);
}

// ---------------- merged setup: LN-folded weights + bf16 weight conversion ----------------
__global__ __launch_bounds__(256) void setup_k(
    const float* __restrict__ wr0, const float* __restrict__ br0,
    const float* __restrict__ wr1, const float* __restrict__ br1,
    const float* __restrict__ wr2, const float* __restrict__ br2,
    const float* __restrict__ g,  const float* __restrict__ lb,
    const float* __restrict__ wqkv0, const float* __restrict__ wqkv1, const float* __restrict__ wqkv2,
    const float* __restrict__ we0,   const float* __restrict__ we1,   const float* __restrict__ we2,
    unsigned short* __restrict__ wg_bf, float* __restrict__ wgsum, float* __restrict__ wbeta,
    unsigned short* __restrict__ wqkv_bf, unsigned short* __restrict__ we_bf)
{
    int blk = blockIdx.x;
    int tid = threadIdx.x;
    if (blk < 3) {
        if (tid < 144) {
            int l = blk, e = tid;
            const float* wr = (l == 0) ? wr0 : ((l == 1) ? wr1 : wr2);
            const float* br = (l == 0) ? br0 : ((l == 1) ? br1 : br2);
            float sg = 0.f, sb = 0.f;
            for (int d = 0; d < DD; ++d) {
                float w = wr[e * DD + d];
                float wgv = w * g[d];
                wg_bf[((size_t)l * EE + e) * DD + d] = f2bf(wgv);
                sg += wgv;
                sb += w * lb[d];
            }
            wgsum[l * EE + e] = sg;
            wbeta[l * EE + e] = sb + br[e];
        }
        return;
    }
    int idx = (blk - 3) * 256 + tid;
    const int T1 = 3 * MQKV * 160;
    const int T2 = 3 * 288 * 160;
    if (idx < T1) {
        int l = idx / (MQKV * 160), r = idx % (MQKV * 160);
        int m = r / 160, k = r % 160;
        const float* w = (l == 0) ? wqkv0 : ((l == 1) ? wqkv1 : wqkv2);
        float v = 0.f;
        if (k < 144) {
            if (m < 192) {
                int h = m / 24, j = m % 24;
                if (j < 18) v = w[(h * 18 + j) * 144 + k] * QSCALE;
            } else if (m < 384) {
                int mm = m - 192, h = mm / 24, j = mm % 24;
                if (j < 18) v = w[(144 + h * 18 + j) * 144 + k];
            } else {
                int mm = m - 384;
                if (mm < 144) v = w[(288 + mm) * 144 + k];   // rows 528..575 are zero pad
            }
        }
        wqkv_bf[idx] = f2bf(v);
    } else if (idx < T1 + T2) {
        int j = idx - T1;
        int l = j / (288 * 160), r = j % (288 * 160);
        int m = r / 160, k = r % 160;
        const float* w = (l == 0) ? we0 : ((l == 1) ? we1 : we2);
        we_bf[j] = (k < 144) ? f2bf(w[m * 144 + k]) : 0;
    }
}

// ---------------- fused unfold + LN + reduction-GEMM (replaces unfold_k + gemm1) ----------------
__global__ __launch_bounds__(512) void fgemm1_k(
    const float* __restrict__ t, const unsigned short* __restrict__ wg,
    const float* __restrict__ wgsum, const float* __restrict__ wbeta,
    unsigned short* __restrict__ xrT)
{
    __shared__ unsigned short Cs[64 * 296];       // [tok][d pad 296] 37.9 KB
    __shared__ float red1[8][64], red2[8][64];
    int tid = threadIdx.x;
    int lane = tid & 63, part = tid >> 6;         // token = lane, channel-part = tid>>6
    int b = blockIdx.x >> 6, nc = blockIdx.x & 63;
    int w = lane;
    const float* tb = t + (size_t)b * CC * HH * WW;
    __attribute__((aligned(8))) unsigned short loc[36];
    float s1 = 0.f, s2 = 0.f;
    #pragma unroll
    for (int c4 = 0; c4 < 4; ++c4) {
        int c = part * 4 + c4;
        const float* tc = tb + (size_t)c * 4096;
        #pragma unroll
        for (int i = 0; i < 3; ++i) {
            int hr = nc + i - 1;
            bool rok = ((unsigned)hr < 64u);
            #pragma unroll
            for (int j = 0; j < 3; ++j) {
                int wc = w + j - 1;
                bool ok = rok && ((unsigned)wc < 64u);
                float v = ok ? tc[hr * 64 + wc] : 0.f;
                loc[c4 * 9 + i * 3 + j] = f2bf(v);
                s1 += v;
                s2 = fmaf(v, v, s2);
            }
        }
    }
    {
        unsigned short* cr = &Cs[lane * 296 + part * 36];
        #pragma unroll
        for (int k = 0; k < 9; ++k)
            *(unsigned long long*)&cr[k * 4] = *(const unsigned long long*)&loc[k * 4];
    }
    red1[part][lane] = s1;
    red2[part][lane] = s2;
    __syncthreads();
    if (tid < 64) {
        float a = 0.f, q = 0.f;
        #pragma unroll
        for (int p = 0; p < 8; ++p) { a += red1[p][tid]; q += red2[p][tid]; }
        float m = a * (1.f / 288.f);
        float var = q * (1.f / 288.f) - m * m;
        red1[0][tid] = m;
        red2[0][tid] = rsqrtf(var + 1e-5f);
    }
    __syncthreads();

    // GEMM: wave (tw = token-16 slice, mh = m-tile parity); m-tiles mh, mh+2, ... (5 or 4)
    int l15 = lane & 15, l4 = lane >> 4;
    int tw = part & 3, mh = part >> 2;
    const unsigned short* Ar = wg + (size_t)(mh * 16 + l15) * DD + l4 * 8;
    floatx4 acc[5];
    #pragma unroll
    for (int i = 0; i < 5; ++i) acc[i] = (floatx4){0.f, 0.f, 0.f, 0.f};
    #pragma unroll
    for (int ks = 0; ks < 9; ++ks) {
        bf16x8 bfr = *(const bf16x8*)&Cs[(tw * 16 + l15) * 296 + ks * 32 + l4 * 8];
        #pragma unroll
        for (int i = 0; i < 4; ++i) {
            bf16x8 af = *(const bf16x8*)(Ar + (size_t)i * 32 * DD + ks * 32);
            acc[i] = __builtin_amdgcn_mfma_f32_16x16x32_bf16(af, bfr, acc[i], 0, 0, 0);
        }
        if (mh == 0) {
            bf16x8 af = *(const bf16x8*)(Ar + (size_t)4 * 32 * DD + ks * 32);
            acc[4] = __builtin_amdgcn_mfma_f32_16x16x32_bf16(af, bfr, acc[4], 0, 0, 0);
        }
    }

    __syncthreads();                              // Cs reads done; reuse as epilogue scratch
    {
        int tok = tw * 16 + l15;
        float muv = red1[0][tok], rsv = red2[0][tok];
        #pragma unroll
        for (int i = 0; i < 5; ++i) {
            if (i == 4 && mh) break;
            #pragma unroll
            for (int r = 0; r < 4; ++r) {
                int m = (mh + 2 * i) * 16 + l4 * 4 + r;
                float v = rsv * (acc[i][r] - muv * wgsum[m]) + wbeta[m];
                Cs[tok * 296 + m] = f2bf(v);
            }
        }
    }
    __syncthreads();
    for (int u = tid; u < 64 * 20; u += 512) {
        int row = u / 20, seg = u - row * 20;
        unsigned short* dst = xrT + ((size_t)b * NTOK + nc * 64 + row) * 160 + seg * 8;
        u16x8 val = (seg < 18) ? *(const u16x8*)&Cs[row * 296 + seg * 8] : (u16x8)0;
        *(u16x8*)dst = val;
    }
}

// ---------------- bf16 MFMA GEMM, NT=128, 96-row LDS-staged A-tile ----------------
// R12 staged the A-tile; R13 doubles m-rows per block to 96 (LDS 31.5 KB): B-load issue per
// FLOP and block count halve (gemm2 1408->768, gemm3 768->384). Every 48-row sub-group keeps
// the old homogeneous routing; the epilogue loops the verified 48-row machinery 2 halves x
// 2 m-groups. M padded 528->576 for gemm2; the all-pad group (m0g=528) is skipped.
template<int K, int MODE, int NYB>
__global__ __launch_bounds__(256) void mgemm_k(
    const unsigned short* __restrict__ A, const unsigned short* __restrict__ Bt, int BST,
    unsigned short* __restrict__ Ct, unsigned short* __restrict__ Cv, unsigned short* __restrict__ Ck,
    const float* __restrict__ bias)
{
    constexpr int NT = 128;
    constexpr int AST = 168;                       // padded A row stride (elements)
    __shared__ unsigned short As[96 * AST];        // 31.5 KB staged A-tile
    __shared__ unsigned short Ts[64 * 56];         // 7 KB epilogue scratch (>= 48*72), per group
    int flat = blockIdx.x;
    int g  = (flat / (8 * NYB)) * 8 + (flat & 7);  // 128 groups = 4 batches x 32 n-tiles (XCD = g%8)
    int jm = (flat % (8 * NYB)) >> 3;              // m-block within group
    int n0 = (g & 31) * NT;                        // 32 tiles of 128 tokens
    int bI = g >> 5;
    int m0 = jm * 96;
    int tid = threadIdx.x;
    int wv = tid >> 6, lane = tid & 63;
    int l15 = lane & 15, l4 = lane >> 4;

    // stage A-tile: 96 rows x K, coalesced 16B chunks
    {
        const unsigned short* Ag = A + (size_t)m0 * K;
        constexpr int CPR = K / 8;                 // 16B chunks per row (20 for K=160)
        for (int u = tid; u < 96 * CPR; u += 256) {
            int row = u / CPR, cc = u - row * CPR;
            *(u16x8*)&As[row * AST + cc * 8] = *(const u16x8*)(Ag + (size_t)row * K + cc * 8);
        }
    }

    const unsigned short* Brow = Bt + ((size_t)bI * NTOK + n0 + wv * 16 + l15) * BST + l4 * 8;

    floatx4 acc[6][2];
    #pragma unroll
    for (int mi = 0; mi < 6; ++mi)
        #pragma unroll
        for (int hf = 0; hf < 2; ++hf)
            acc[mi][hf] = (floatx4){0.f, 0.f, 0.f, 0.f};

    __syncthreads();                               // As ready

    #pragma unroll
    for (int ks = 0; ks < K / 32; ++ks) {
        bf16x8 b0 = *(const bf16x8*)(Brow + ks * 32);
        bf16x8 b1 = *(const bf16x8*)(Brow + (size_t)64 * BST + ks * 32);
        #pragma unroll
        for (int mi = 0; mi < 6; ++mi) {
            bf16x8 af = *(const bf16x8*)&As[(mi * 16 + l15) * AST + ks * 32 + l4 * 8];
            acc[mi][0] = __builtin_amdgcn_mfma_f32_16x16x32_bf16(af, b0, acc[mi][0], 0, 0, 0);
            acc[mi][1] = __builtin_amdgcn_mfma_f32_16x16x32_bf16(af, b1, acc[mi][1], 0, 0, 0);
        }
    }

    int n_l = wv * 16 + l15;                        // token col within 64-half (0..63)

    #pragma unroll
    for (int hf = 0; hf < 2; ++hf) {
        int n0h = n0 + hf * 64;
        #pragma unroll
        for (int mg = 0; mg < 2; ++mg) {
            int m0g = m0 + mg * 48;
            __syncthreads();                        // As reads done (first) / prior Ts reads done
            if (MODE == 0 && m0g >= 528) continue;  // all-pad group (block-uniform)
            if (MODE == 2) {
                #pragma unroll
                for (int mi = 0; mi < 3; ++mi)
                    #pragma unroll
                    for (int r = 0; r < 4; ++r) {
                        int m_l = mi * 16 + l4 * 4 + r;
                        Ts[m_l * 72 + n_l] = f2bf(acc[mg * 3 + mi][hf][r] + bias[m0g + m_l]);
                    }
                __syncthreads();
                for (int u = tid; u < 48 * 8; u += 256) {
                    int row = u >> 3, seg = u & 7;
                    unsigned short* dst = Ct + ((size_t)bI * DD + m0g + row) * NTOK + n0h + seg * 8;
                    *(u16x8*)dst = *(const u16x8*)&Ts[row * 72 + seg * 8];
                }
            } else {
                bool vpath = (m0g >= 384);
                #pragma unroll
                for (int mi = 0; mi < 3; ++mi)
                    #pragma unroll
                    for (int r = 0; r < 4; ++r) {
                        int m_l = mi * 16 + l4 * 4 + r;
                        float v = acc[mg * 3 + mi][hf][r];
                        if (!vpath) Ts[n_l * 56 + m_l] = f2bf(v);
                        else        Ts[m_l * 72 + n_l] = f2bf(v);
                    }
                __syncthreads();
                if (!vpath) {
                    if (tid < 128) {
                        int row = tid >> 1, half = tid & 1;
                        const unsigned short* src = &Ts[row * 56 + half * 24];
                        if (m0g >= 192) {
                            // K -> packed 64B rows: kP[b][head][tok][32], cols 24..31 zeroed
                            int head = (m0g - 192) / 24 + half;
                            unsigned short* dst = Ck + ((size_t)(bI * 8 + head) * NTOK + n0h + row) * KST;
                            #pragma unroll
                            for (int u = 0; u < 3; ++u)
                                *(u16x8*)&dst[u * 8] = *(const u16x8*)&src[u * 8];
                            *(u16x8*)&dst[24] = (u16x8)0;
                        } else {
                            unsigned short* dst = Ct + ((size_t)bI * NTOK + n0h + row) * QST + m0g + half * 24;
                            #pragma unroll
                            for (int u = 0; u < 3; ++u)
                                *(u16x8*)&dst[u * 8] = *(const u16x8*)&src[u * 8];
                        }
                    }
                } else {
                    for (int u = tid; u < 48 * 8; u += 256) {
                        int row = u >> 3, seg = u & 7;
                        unsigned short* dst = Cv + ((size_t)bI * EE + (m0g - 384) + row) * NTOK + n0h + seg * 8;
                        *(u16x8*)dst = *(const u16x8*)&Ts[row * 72 + seg * 8];
                    }
                }
            }
        }
    }
}

// ---------------- MFMA bf16 attention: 2-wave blocks, dbuf Vs, bare v_exp + setprio (frozen) ----------------
__global__ __launch_bounds__(128) void attn_k2(const unsigned short* __restrict__ qT,
                                               const unsigned short* __restrict__ kP,
                                               const unsigned short* __restrict__ vF,
                                               unsigned short* __restrict__ oT)
{
    __shared__ unsigned short Vs[2][32 * 136];    // [buf][d][tok pad 136]; rows 18..30 zero, 31 ones

    int blk = blockIdx.x;
    int bhs = blk & 127;                          // blocks sharing K/V are 128 apart -> same XCD
    int qc  = blk >> 7;                           // 16 chunks of 64 q
    int b = bhs >> 5, h = (bhs >> 2) & 7, s = bhs & 3;
    int tid  = threadIdx.x;
    int wv   = tid >> 6;                          // 0..1
    int lane = tid & 63;
    int l15 = lane & 15, l4 = lane >> 4;
    int q0 = qc * 64;
    int tokbase = s * 1024;

    // pad rows 18..31 of both buffers once (staging only rewrites rows 0..17)
    for (int v = tid; v < 14 * 16; v += 128) {
        int d = 18 + (v >> 4), seg = v & 15;
        unsigned short val = (d == 31) ? (unsigned short)0x3F80 : (unsigned short)0;
        u16x8 vv = (u16x8)val;
        *(u16x8*)&Vs[0][d * 136 + seg * 8] = vv;
        *(u16x8*)&Vs[1][d * 136 + seg * 8] = vv;
    }

    bf16x8 qf[2];                                 // B-frag: col=q(l15), k=d(l4*8+j)
    #pragma unroll
    for (int ni = 0; ni < 2; ++ni) {
        u16x8 raw = *(const u16x8*)(qT + ((size_t)b * NTOK + tokbase + q0 + wv * 32 + ni * 16 + l15) * QST
                                    + 24 * h + l4 * 8);
        if (l4 == 3) raw = (u16x8)0;
        qf[ni] = *(bf16x8*)&raw;
    }

    floatx4 oacc[2][2];                           // [ni][nd]; O^T rows d=nd*16+l4*4+r, col q
    #pragma unroll
    for (int ni = 0; ni < 2; ++ni)
        #pragma unroll
        for (int nd = 0; nd < 2; ++nd)
            oacc[ni][nd] = (floatx4){0.f, 0.f, 0.f, 0.f};

    // V staging: 288 16B-chunks per 128-tok round over 128 threads (chunks tid, tid+128, tid+256)
    const unsigned short* vbb = vF + (size_t)b * EE * NTOK + tokbase;
    int seg0 = tid & 15;
    int d0 = tid >> 4;                            // d 0..7
    int d1 = 8 + (tid >> 4);                      // d 8..15
    bool x2 = (tid < 32);
    int d2 = 16 + (tid >> 4);                     // d 16..17 (tid<32)
    const unsigned short* vsrc0 = vbb + (size_t)(h * 18 + d0) * NTOK + seg0 * 8;
    const unsigned short* vsrc1 = vbb + (size_t)(h * 18 + d1) * NTOK + seg0 * 8;
    const unsigned short* vsrc2 = vbb + (size_t)(h * 18 + d2) * NTOK + seg0 * 8;

    // prologue: round 0 -> Vs[0]; preload round-1 V into regs
    {
        u16x8 v0 = *(const u16x8*)vsrc0;
        u16x8 v1 = *(const u16x8*)vsrc1;
        *(u16x8*)&Vs[0][d0 * 136 + seg0 * 8] = v0;
        *(u16x8*)&Vs[0][d1 * 136 + seg0 * 8] = v1;
        if (x2) {
            u16x8 v2 = *(const u16x8*)vsrc2;
            *(u16x8*)&Vs[0][d2 * 136 + seg0 * 8] = v2;
        }
    }
    u16x8 pv0 = *(const u16x8*)(vsrc0 + 128);
    u16x8 pv1 = *(const u16x8*)(vsrc1 + 128);
    u16x8 pv2;
    if (x2) pv2 = *(const u16x8*)(vsrc2 + 128);

    const unsigned short* kRow = kP + ((size_t)(b * 8 + h) * NTOK + tokbase + l15) * KST + l4 * 8;
    __syncthreads();

    for (int c0 = 0; c0 < 1024; c0 += 128) {
        const int cur = (c0 >> 7) & 1;
        int cn = c0 + 128;
        // write next round's V into the other buffer; start loading round r+2
        if (cn < 1024) {
            *(u16x8*)&Vs[cur ^ 1][d0 * 136 + seg0 * 8] = pv0;
            *(u16x8*)&Vs[cur ^ 1][d1 * 136 + seg0 * 8] = pv1;
            if (x2) *(u16x8*)&Vs[cur ^ 1][d2 * 136 + seg0 * 8] = pv2;
            int cn2 = c0 + 256;
            if (cn2 < 1024) {
                pv0 = *(const u16x8*)(vsrc0 + cn2);
                pv1 = *(const u16x8*)(vsrc1 + cn2);
                if (x2) pv2 = *(const u16x8*)(vsrc2 + cn2);
            }
        }

        // K for the whole round (compiler's vmcnt lets sub1's 4 loads fly under sub0 compute)
        bf16x8 kreg[8];
        #pragma unroll
        for (int i = 0; i < 8; ++i) {
            u16x8 raw = *(const u16x8*)(kRow + (unsigned)(c0 + i * 16) * KST);
            kreg[i] = *(bf16x8*)&raw;
        }

        #pragma unroll
        for (int sub = 0; sub < 2; ++sub) {
            unsigned int pk0[2][4], pk1[2][4];    // [ni][mi] — transient within sub
            #pragma unroll
            for (int ni = 0; ni < 2; ++ni) {
                floatx4 sacc[4];
                __builtin_amdgcn_s_setprio(1);
                #pragma unroll
                for (int mi = 0; mi < 4; ++mi) {
                    floatx4 z = (floatx4){0.f, 0.f, 0.f, 0.f};
                    sacc[mi] = __builtin_amdgcn_mfma_f32_16x16x32_bf16(kreg[sub * 4 + mi], qf[ni], z, 0, 0, 0);
                }
                __builtin_amdgcn_s_setprio(0);
                #pragma unroll
                for (int mi = 0; mi < 4; ++mi) {
                    pk0[ni][mi] = pack_bf_trunc(fexp2(sacc[mi][0]), fexp2(sacc[mi][1]));
                    pk1[ni][mi] = pack_bf_trunc(fexp2(sacc[mi][2]), fexp2(sacc[mi][3]));
                }
            }

            // PV: af read once per (c,nd), shared by both ni q-groups
            #pragma unroll
            for (int c = 0; c < 2; ++c) {
                union { unsigned int u[4]; bf16x8 v; } bfr[2];
                #pragma unroll
                for (int ni = 0; ni < 2; ++ni) {
                    unsigned int B0 = pk0[ni][2 * c], B2 = pk0[ni][2 * c + 1];
                    unsigned int B1 = pk1[ni][2 * c], B3 = pk1[ni][2 * c + 1];
                    plswap32(B0, B2); plswap16(B0, B2);
                    plswap32(B1, B3); plswap16(B1, B3);
                    bfr[ni].u[0] = B0; bfr[ni].u[1] = B1; bfr[ni].u[2] = B2; bfr[ni].u[3] = B3;
                }
                __builtin_amdgcn_s_setprio(1);
                #pragma unroll
                for (int nd = 0; nd < 2; ++nd) {
                    bf16x8 af = *(const bf16x8*)&Vs[cur][(nd * 16 + l15) * 136 + sub * 64 + c * 32 + l4 * 8];
                    #pragma unroll
                    for (int ni = 0; ni < 2; ++ni)
                        oacc[ni][nd] = __builtin_amdgcn_mfma_f32_16x16x32_bf16(af, bfr[ni].v,
                                                                               oacc[ni][nd], 0, 0, 0);
                }
                __builtin_amdgcn_s_setprio(0);
            }
        }

        __syncthreads();                          // reads of Vs[cur] done; next round may overwrite
    }

    // row-sum sits at d=31 (ones row of Vs): oacc[ni][1][3] on lanes l4=3, col=q=l15
    #pragma unroll
    for (int ni = 0; ni < 2; ++ni) {
        float lsum = __shfl(oacc[ni][1][3], 48 + l15, 64);
        float inv  = 1.f / lsum;
        size_t rowi = (size_t)b * NTOK + tokbase + q0 + wv * 32 + ni * 16 + l15;
        unsigned short* orow = oT + rowi * 160 + h * 18;
        unsigned int w0 = (unsigned)f2bf(oacc[ni][0][0] * inv) | ((unsigned)f2bf(oacc[ni][0][1] * inv) << 16);
        unsigned int w1 = (unsigned)f2bf(oacc[ni][0][2] * inv) | ((unsigned)f2bf(oacc[ni][0][3] * inv) << 16);
        *(unsigned int*)&orow[l4 * 4]     = w0;   // d = 4*l4 + 0,1
        *(unsigned int*)&orow[l4 * 4 + 2] = w1;   // d = 4*l4 + 2,3
        if (l4 == 0) {                            // d = 16,17
            unsigned int w2 = (unsigned)f2bf(oacc[ni][1][0] * inv) | ((unsigned)f2bf(oacc[ni][1][1] * inv) << 16);
            *(unsigned int*)&orow[16] = w2;
        }
        if (h == 7 && l4 < 2) {                   // zero pad cols 144..159
            u16x8 z = (u16x8)0;
            *(u16x8*)(oT + rowi * 160 + 144 + l4 * 8) = z;
        }
    }
}

// ---------------- fold (bf16 cols) + masked residual, 8-pixel vectorized threads ----------------
__global__ __launch_bounds__(256) void fold_k(const unsigned short* __restrict__ cols,
                                              const float* __restrict__ tprev,
                                              float* __restrict__ t)
{
    int base = blockIdx.x * 2048 + threadIdx.x * 8;   // 8 consecutive w pixels
    int w0 = base & 63;                               // multiple of 8
    int h  = (base >> 6) & 63;
    int c  = (base >> 12) & 31;
    int b  = base >> 17;
    const unsigned short* cb = cols + (size_t)b * DD * NTOK + (size_t)c * 9 * NTOK;
    float sum[8];
    #pragma unroll
    for (int p = 0; p < 8; ++p) sum[p] = 0.f;

    #pragma unroll
    for (int i = 0; i < 3; ++i) {
        int hs = h + 1 - i;
        if ((unsigned)hs < 64u) {
            #pragma unroll
            for (int j = 0; j < 3; ++j) {
                const unsigned short* row = cb + (size_t)(i * 3 + j) * NTOK + hs * 64;
                u16x8 mid = *(const u16x8*)&row[w0];          // w0..w0+7
                if (j == 1) {
                    #pragma unroll
                    for (int p = 0; p < 8; ++p) sum[p] += bf2f(mid[p]);
                } else if (j == 0) {                          // ws = w+1
                    #pragma unroll
                    for (int p = 0; p < 7; ++p) sum[p] += bf2f(mid[p + 1]);
                    if (w0 < 56) sum[7] += bf2f(row[w0 + 8]); // w0==56 -> px7 ws=64 masked
                } else {                                      // j==2: ws = w-1
                    if (w0 > 0) sum[0] += bf2f(row[w0 - 1]);  // w0==0 -> px0 ws=-1 masked
                    #pragma unroll
                    for (int p = 1; p < 8; ++p) sum[p] += bf2f(mid[p - 1]);
                }
            }
        }
    }
    int ch = (h == 0 || h == 63) ? 2 : 3;
    const float* tp = tprev + base;
    float out[8];
    #pragma unroll
    for (int p = 0; p < 8; ++p) {
        int wp = w0 + p;
        int cw_ = (wp == 0 || wp == 63) ? 2 : 3;
        out[p] = sum[p] + (float)(ch * cw_) * tp[p];
    }
    *(float4*)&t[base]     = *(const float4*)&out[0];
    *(float4*)&t[base + 4] = *(const float4*)&out[4];
}

// ---------------- conv3x3 + ELU + residual, 4-pixel register strips ----------------
__global__ __launch_bounds__(256) void conv_k(const float* __restrict__ t,
    const float* __restrict__ cw, const float* __restrict__ cbias,
    const float* __restrict__ x, float* __restrict__ out)
{
    __shared__ float wsh[CC * 9];
    int blk = blockIdx.x;
    int band = blk & 3, co = (blk >> 2) & 31, b = blk >> 7;
    int tid = threadIdx.x;
    for (int u = tid; u < CC * 9; u += 256) wsh[u] = cw[co * CC * 9 + u];
    __syncthreads();
    int h = band * 16 + (tid >> 4);
    int w0 = (tid & 15) << 2;
    const float* tb = t + (size_t)b * CC * 4096;
    float bias = cbias[co];
    float a0 = bias, a1 = bias, a2 = bias, a3 = bias;
    for (int ci = 0; ci < CC; ++ci) {
        const float* tc = tb + (size_t)ci * 4096;
        const float* wr = &wsh[ci * 9];
        #pragma unroll
        for (int i = 0; i < 3; ++i) {
            int hr = h + i - 1;
            if ((unsigned)hr < 64u) {
                const float* row = tc + hr * 64;
                float vl = (w0 > 0)  ? row[w0 - 1] : 0.f;
                float4 c4 = *(const float4*)&row[w0];
                float vr = (w0 < 60) ? row[w0 + 4] : 0.f;
                float wj0 = wr[i * 3], wj1 = wr[i * 3 + 1], wj2 = wr[i * 3 + 2];
                a0 = fmaf(wj0, vl,   a0); a0 = fmaf(wj1, c4.x, a0); a0 = fmaf(wj2, c4.y, a0);
                a1 = fmaf(wj0, c4.x, a1); a1 = fmaf(wj1, c4.y, a1); a1 = fmaf(wj2, c4.z, a1);
                a2 = fmaf(wj0, c4.y, a2); a2 = fmaf(wj1, c4.z, a2); a2 = fmaf(wj2, c4.w, a2);
                a3 = fmaf(wj0, c4.z, a3); a3 = fmaf(wj1, c4.w, a3); a3 = fmaf(wj2, vr,   a3);
            }
        }
    }
    size_t oidx = ((size_t)(b * CC + co) * 4096) + h * 64 + w0;
    float4 xin = *(const float4*)&x[oidx];
    float4 o;
    o.x = xin.x + ((a0 > 0.f) ? a0 : (__expf(a0) - 1.f));
    o.y = xin.y + ((a1 > 0.f) ? a1 : (__expf(a1) - 1.f));
    o.z = xin.z + ((a2 > 0.f) ? a2 : (__expf(a2) - 1.f));
    o.w = xin.w + ((a3 > 0.f) ? a3 : (__expf(a3) - 1.f));
    *(float4*)&out[oidx] = o;
}

extern "C" void kernel_launch(void* const* d_in, const int* in_sizes, int n_in,
                              void* d_out, int out_size, void* d_ws, size_t ws_size,
                              hipStream_t stream)
{
    const float* x    = (const float*)d_in[0];
    const float* ln_g = (const float*)d_in[1];
    const float* ln_b = (const float*)d_in[2];
    const float* cw   = (const float*)d_in[3];
    const float* cb   = (const float*)d_in[4];
    const float* wr[3]   = {(const float*)d_in[5],  (const float*)d_in[10], (const float*)d_in[15]};
    const float* br[3]   = {(const float*)d_in[6],  (const float*)d_in[11], (const float*)d_in[16]};
    const float* wqkv[3] = {(const float*)d_in[7],  (const float*)d_in[12], (const float*)d_in[17]};
    const float* we[3]   = {(const float*)d_in[8],  (const float*)d_in[13], (const float*)d_in[18]};
    const float* be[3]   = {(const float*)d_in[9],  (const float*)d_in[14], (const float*)d_in[19]};
    float* out = (float*)d_out;

    char* p = (char*)d_ws;
    unsigned short* cols_bf = (unsigned short*)p; p += (size_t)BN * DD * NTOK * 2; // 9.4 MB (emha out, bf16)
    unsigned short* oT    = (unsigned short*)p; p += (size_t)BN * NTOK * 288 * 2;  // 9.4 MB (attn out, 160-stride)
    unsigned short* xrT   = (unsigned short*)p; p += (size_t)BN * NTOK * 160 * 2;  // 5.2 MB
    unsigned short* qT    = (unsigned short*)p; p += (size_t)BN * NTOK * QST * 2;  // 6.3 MB (Q only)
    unsigned short* kP    = (unsigned short*)p; p += (size_t)BN * 8 * NTOK * KST * 2; // 8.4 MB (packed K, 64B rows; MUST follow qT: qf tail overread)
    unsigned short* vF    = (unsigned short*)p; p += (size_t)BN * EE * NTOK * 2;   // 4.7 MB
    float* tA   = (float*)p;              p += (size_t)BN * CC * HH * WW * 4;
    float* tB   = (float*)p;              p += (size_t)BN * CC * HH * WW * 4;
    unsigned short* wg_bf   = (unsigned short*)p; p += (size_t)3 * EE * DD * 2;
    unsigned short* wqkv_bf = (unsigned short*)p; p += (size_t)3 * MQKV * 160 * 2;
    unsigned short* we_bf   = (unsigned short*)p; p += (size_t)3 * DD * 160 * 2;
    float* wgsum = (float*)p;             p += 3 * EE * 4;
    float* wbeta = (float*)p;             p += 3 * EE * 4;
    (void)in_sizes; (void)n_in; (void)out_size; (void)ws_size;

    // grid: 3 + ceil((3*MQKV*160 + 3*288*160)/256) = 3 + 1620
    setup_k<<<1623, 256, 0, stream>>>(wr[0], br[0], wr[1], br[1], wr[2], br[2], ln_g, ln_b,
                                      wqkv[0], wqkv[1], wqkv[2], we[0], we[1], we[2],
                                      wg_bf, wgsum, wbeta, wqkv_bf, we_bf);

    const float* tin = x;
    float* touts[3] = {tA, tB, tA};
    for (int l = 0; l < 3; ++l) {
        // fused unfold + LN + gemm1
        fgemm1_k<<<256, 512, 0, stream>>>(tin, wg_bf + (size_t)l * EE * DD,
                                          wgsum + l * EE, wbeta + l * EE, xrT);
        // gemm2: K=160, M=576 (6 x 96-row blocks) -> grid 768
        mgemm_k<160, 0, 6><<<768, 256, 0, stream>>>(
            wqkv_bf + (size_t)l * MQKV * 160, xrT, 160, qT, vF, kP, nullptr);
        attn_k2<<<2048, 128, 0, stream>>>(qT, kP, vF, oT);
        // gemm3: K=160, M=288 (3 x 96-row blocks) -> grid 384
        mgemm_k<160, 2, 3><<<384, 256, 0, stream>>>(
            we_bf + (size_t)l * DD * 160, oT, 160, cols_bf, nullptr, nullptr, be[l]);
        fold_k<<<256, 256, 0, stream>>>(cols_bf, tin, touts[l]);
        tin = touts[l];
    }
    conv_k<<<512, 256, 0, stream>>>(tA, cw, cb, x, out);
}

// Round 14
// 366.485 us; speedup vs baseline: 1.0133x; 1.0133x over previous
//
#include <hip/hip_runtime.h>
#include <math.h>

#define BN 4
#define CC 32
#define HH 64
#define WW 64
#define DD 288          // C*K*K
#define EE 144
#define NTOK 4096
#define SCALE_F 0.2357022603955158f           // 18^-0.5
#define QSCALE  0.3401074286f                 // SCALE_F * log2(e)
#define QST 192         // qT row stride: 8 heads * 24 (Q only)
#define KST 32          // kP row stride: 24 real + 8 zero pad (64B rows)
#define MQKV 528        // padded QKV GEMM M: 192 Q + 192 K + 144 V

typedef __bf16 bf16x8 __attribute__((ext_vector_type(8)));
typedef float floatx4 __attribute__((ext_vector_type(4)));
typedef unsigned short u16x8 __attribute__((ext_vector_type(8)));

__device__ __forceinline__ unsigned short f2bf(float x) {
    unsigned int u = __float_as_uint(x);
    u += 0x7fffu + ((u >> 16) & 1u);          // RNE
    return (unsigned short)(u >> 16);
}
__device__ __forceinline__ float bf2f(unsigned short s) {
    return __uint_as_float(((unsigned int)s) << 16);
}
// pack hi16(a), hi16(b) -> (b_hi<<16)|a_hi  — single v_perm_b32
__device__ __forceinline__ unsigned int pack_bf_trunc(float a, float b) {
    return __builtin_amdgcn_perm(__float_as_uint(b), __float_as_uint(a), 0x07060302u);
}
// gfx950 cross-lane row swaps (both operands read+written)
__device__ __forceinline__ void plswap32(unsigned int& a, unsigned int& b) {
    asm("v_permlane32_swap_b32 %0, %1" : "+v"(a), "+v"(b));
}
__device__ __forceinline__ void plswap16(unsigned int& a, unsigned int& b) {
    asm("v_permlane16_swap_b32 %0, %1" : "+v"(a), "+v"(b));
}
// bare v_exp_f32 (2^x) — OCML exp2f carries range/denorm fixup VALU (R8: -14 us/dispatch)
__device__ __forceinline__ float fexp2(float x) {
    return __builtin_amdgcn_exp2f(x);
}

// ---------------- merged setup: LN-folded weights + bf16 weight conversion ----------------
__global__ __launch_bounds__(256) void setup_k(
    const float* __restrict__ wr0, const float* __restrict__ br0,
    const float* __restrict__ wr1, const float* __restrict__ br1,
    const float* __restrict__ wr2, const float* __restrict__ br2,
    const float* __restrict__ g,  const float* __restrict__ lb,
    const float* __restrict__ wqkv0, const float* __restrict__ wqkv1, const float* __restrict__ wqkv2,
    const float* __restrict__ we0,   const float* __restrict__ we1,   const float* __restrict__ we2,
    unsigned short* __restrict__ wg_bf, float* __restrict__ wgsum, float* __restrict__ wbeta,
    unsigned short* __restrict__ wqkv_bf, unsigned short* __restrict__ we_bf)
{
    int blk = blockIdx.x;
    int tid = threadIdx.x;
    if (blk < 3) {
        if (tid < 144) {
            int l = blk, e = tid;
            const float* wr = (l == 0) ? wr0 : ((l == 1) ? wr1 : wr2);
            const float* br = (l == 0) ? br0 : ((l == 1) ? br1 : br2);
            float sg = 0.f, sb = 0.f;
            for (int d = 0; d < DD; ++d) {
                float w = wr[e * DD + d];
                float wgv = w * g[d];
                wg_bf[((size_t)l * EE + e) * DD + d] = f2bf(wgv);
                sg += wgv;
                sb += w * lb[d];
            }
            wgsum[l * EE + e] = sg;
            wbeta[l * EE + e] = sb + br[e];
        }
        return;
    }
    int idx = (blk - 3) * 256 + tid;
    const int T1 = 3 * MQKV * 160;
    const int T2 = 3 * 288 * 160;
    if (idx < T1) {
        int l = idx / (MQKV * 160), r = idx % (MQKV * 160);
        int m = r / 160, k = r % 160;
        const float* w = (l == 0) ? wqkv0 : ((l == 1) ? wqkv1 : wqkv2);
        float v = 0.f;
        if (k < 144) {
            if (m < 192) {
                int h = m / 24, j = m % 24;
                if (j < 18) v = w[(h * 18 + j) * 144 + k] * QSCALE;
            } else if (m < 384) {
                int mm = m - 192, h = mm / 24, j = mm % 24;
                if (j < 18) v = w[(144 + h * 18 + j) * 144 + k];
            } else {
                v = w[(288 + (m - 384)) * 144 + k];
            }
        }
        wqkv_bf[idx] = f2bf(v);
    } else if (idx < T1 + T2) {
        int j = idx - T1;
        int l = j / (288 * 160), r = j % (288 * 160);
        int m = r / 160, k = r % 160;
        const float* w = (l == 0) ? we0 : ((l == 1) ? we1 : we2);
        we_bf[j] = (k < 144) ? f2bf(w[m * 144 + k]) : 0;
    }
}

// ---------------- fused unfold + LN + reduction-GEMM (replaces unfold_k + gemm1) ----------------
__global__ __launch_bounds__(512) void fgemm1_k(
    const float* __restrict__ t, const unsigned short* __restrict__ wg,
    const float* __restrict__ wgsum, const float* __restrict__ wbeta,
    unsigned short* __restrict__ xrT)
{
    __shared__ unsigned short Cs[64 * 296];       // [tok][d pad 296] 37.9 KB
    __shared__ float red1[8][64], red2[8][64];
    int tid = threadIdx.x;
    int lane = tid & 63, part = tid >> 6;         // token = lane, channel-part = tid>>6
    int b = blockIdx.x >> 6, nc = blockIdx.x & 63;
    int w = lane;
    const float* tb = t + (size_t)b * CC * HH * WW;
    __attribute__((aligned(8))) unsigned short loc[36];
    float s1 = 0.f, s2 = 0.f;
    #pragma unroll
    for (int c4 = 0; c4 < 4; ++c4) {
        int c = part * 4 + c4;
        const float* tc = tb + (size_t)c * 4096;
        #pragma unroll
        for (int i = 0; i < 3; ++i) {
            int hr = nc + i - 1;
            bool rok = ((unsigned)hr < 64u);
            #pragma unroll
            for (int j = 0; j < 3; ++j) {
                int wc = w + j - 1;
                bool ok = rok && ((unsigned)wc < 64u);
                float v = ok ? tc[hr * 64 + wc] : 0.f;
                loc[c4 * 9 + i * 3 + j] = f2bf(v);
                s1 += v;
                s2 = fmaf(v, v, s2);
            }
        }
    }
    {
        unsigned short* cr = &Cs[lane * 296 + part * 36];
        #pragma unroll
        for (int k = 0; k < 9; ++k)
            *(unsigned long long*)&cr[k * 4] = *(const unsigned long long*)&loc[k * 4];
    }
    red1[part][lane] = s1;
    red2[part][lane] = s2;
    __syncthreads();
    if (tid < 64) {
        float a = 0.f, q = 0.f;
        #pragma unroll
        for (int p = 0; p < 8; ++p) { a += red1[p][tid]; q += red2[p][tid]; }
        float m = a * (1.f / 288.f);
        float var = q * (1.f / 288.f) - m * m;
        red1[0][tid] = m;
        red2[0][tid] = rsqrtf(var + 1e-5f);
    }
    __syncthreads();

    // GEMM: wave (tw = token-16 slice, mh = m-tile parity); m-tiles mh, mh+2, ... (5 or 4)
    int l15 = lane & 15, l4 = lane >> 4;
    int tw = part & 3, mh = part >> 2;
    const unsigned short* Ar = wg + (size_t)(mh * 16 + l15) * DD + l4 * 8;
    floatx4 acc[5];
    #pragma unroll
    for (int i = 0; i < 5; ++i) acc[i] = (floatx4){0.f, 0.f, 0.f, 0.f};
    #pragma unroll
    for (int ks = 0; ks < 9; ++ks) {
        bf16x8 bfr = *(const bf16x8*)&Cs[(tw * 16 + l15) * 296 + ks * 32 + l4 * 8];
        #pragma unroll
        for (int i = 0; i < 4; ++i) {
            bf16x8 af = *(const bf16x8*)(Ar + (size_t)i * 32 * DD + ks * 32);
            acc[i] = __builtin_amdgcn_mfma_f32_16x16x32_bf16(af, bfr, acc[i], 0, 0, 0);
        }
        if (mh == 0) {
            bf16x8 af = *(const bf16x8*)(Ar + (size_t)4 * 32 * DD + ks * 32);
            acc[4] = __builtin_amdgcn_mfma_f32_16x16x32_bf16(af, bfr, acc[4], 0, 0, 0);
        }
    }

    __syncthreads();                              // Cs reads done; reuse as epilogue scratch
    {
        int tok = tw * 16 + l15;
        float muv = red1[0][tok], rsv = red2[0][tok];
        #pragma unroll
        for (int i = 0; i < 5; ++i) {
            if (i == 4 && mh) break;
            #pragma unroll
            for (int r = 0; r < 4; ++r) {
                int m = (mh + 2 * i) * 16 + l4 * 4 + r;
                float v = rsv * (acc[i][r] - muv * wgsum[m]) + wbeta[m];
                Cs[tok * 296 + m] = f2bf(v);
            }
        }
    }
    __syncthreads();
    for (int u = tid; u < 64 * 20; u += 512) {
        int row = u / 20, seg = u - row * 20;
        unsigned short* dst = xrT + ((size_t)b * NTOK + nc * 64 + row) * 160 + seg * 8;
        u16x8 val = (seg < 18) ? *(const u16x8*)&Cs[row * 296 + seg * 8] : (u16x8)0;
        *(u16x8*)dst = val;
    }
}

// ---------------- bf16 MFMA GEMM, NT=128, LDS-staged A-tile (R12 config, best measured) ----------------
// 48-row m-blocks: R13's 96-row variant regressed (LDS 31.5KB cut blocks/CU; B-issue wasn't
// binding). A-tile staged in LDS once per block (coalesced), padded row stride 168 elem
// (336B: 16B-aligned b128 reads, bank step 20 mod 32 -> free 2-way conflicts).
// MODE 0 epilogue routes: m0<192 -> qT; 192<=m0<384 -> kP packed; m0>=384 -> vF. MODE 2 -> cols.
template<int K, int MODE, int NYB>
__global__ __launch_bounds__(256) void mgemm_k(
    const unsigned short* __restrict__ A, const unsigned short* __restrict__ Bt, int BST,
    unsigned short* __restrict__ Ct, unsigned short* __restrict__ Cv, unsigned short* __restrict__ Ck,
    const float* __restrict__ bias)
{
    constexpr int NT = 128;
    constexpr int AST = 168;                       // padded A row stride (elements)
    __shared__ unsigned short As[48 * AST];        // 15.75 KB staged A-tile
    __shared__ unsigned short Ts[64 * 56];         // 7 KB epilogue scratch (>= 48*72), per half
    int flat = blockIdx.x;
    int g  = (flat / (8 * NYB)) * 8 + (flat & 7);  // 128 groups = 4 batches x 32 n-tiles (XCD = g%8)
    int jm = (flat % (8 * NYB)) >> 3;              // m-block within group
    int n0 = (g & 31) * NT;                        // 32 tiles of 128 tokens
    int bI = g >> 5;
    int m0 = jm * 48;
    int tid = threadIdx.x;
    int wv = tid >> 6, lane = tid & 63;
    int l15 = lane & 15, l4 = lane >> 4;

    // stage A-tile: 48 rows x K, coalesced 16B chunks
    {
        const unsigned short* Ag = A + (size_t)m0 * K;
        constexpr int CPR = K / 8;                 // 16B chunks per row (20 for K=160)
        for (int u = tid; u < 48 * CPR; u += 256) {
            int row = u / CPR, cc = u - row * CPR;
            *(u16x8*)&As[row * AST + cc * 8] = *(const u16x8*)(Ag + (size_t)row * K + cc * 8);
        }
    }

    const unsigned short* Brow = Bt + ((size_t)bI * NTOK + n0 + wv * 16 + l15) * BST + l4 * 8;

    floatx4 acc[3][2];
    #pragma unroll
    for (int mi = 0; mi < 3; ++mi)
        #pragma unroll
        for (int hf = 0; hf < 2; ++hf)
            acc[mi][hf] = (floatx4){0.f, 0.f, 0.f, 0.f};

    __syncthreads();                               // As ready

    #pragma unroll
    for (int ks = 0; ks < K / 32; ++ks) {
        bf16x8 b0 = *(const bf16x8*)(Brow + ks * 32);
        bf16x8 b1 = *(const bf16x8*)(Brow + (size_t)64 * BST + ks * 32);
        #pragma unroll
        for (int mi = 0; mi < 3; ++mi) {
            bf16x8 af = *(const bf16x8*)&As[(mi * 16 + l15) * AST + ks * 32 + l4 * 8];
            acc[mi][0] = __builtin_amdgcn_mfma_f32_16x16x32_bf16(af, b0, acc[mi][0], 0, 0, 0);
            acc[mi][1] = __builtin_amdgcn_mfma_f32_16x16x32_bf16(af, b1, acc[mi][1], 0, 0, 0);
        }
    }

    int n_l = wv * 16 + l15;                        // token col within 64-half (0..63)

    #pragma unroll
    for (int hf = 0; hf < 2; ++hf) {
        __syncthreads();                            // As reads done (hf=0) / prior Ts reads done (hf=1)
        int n0h = n0 + hf * 64;
        if (MODE == 2) {
            #pragma unroll
            for (int mi = 0; mi < 3; ++mi)
                #pragma unroll
                for (int r = 0; r < 4; ++r) {
                    int m_l = mi * 16 + l4 * 4 + r;
                    Ts[m_l * 72 + n_l] = f2bf(acc[mi][hf][r] + bias[m0 + m_l]);
                }
            __syncthreads();
            for (int u = tid; u < 48 * 8; u += 256) {
                int row = u >> 3, seg = u & 7;
                unsigned short* dst = Ct + ((size_t)bI * DD + m0 + row) * NTOK + n0h + seg * 8;
                *(u16x8*)dst = *(const u16x8*)&Ts[row * 72 + seg * 8];
            }
        } else {
            bool vpath = (m0 >= 384);
            #pragma unroll
            for (int mi = 0; mi < 3; ++mi)
                #pragma unroll
                for (int r = 0; r < 4; ++r) {
                    int m_l = mi * 16 + l4 * 4 + r;
                    float v = acc[mi][hf][r];
                    if (!vpath) Ts[n_l * 56 + m_l] = f2bf(v);
                    else        Ts[m_l * 72 + n_l] = f2bf(v);
                }
            __syncthreads();
            if (!vpath) {
                if (tid < 128) {
                    int row = tid >> 1, half = tid & 1;
                    const unsigned short* src = &Ts[row * 56 + half * 24];
                    if (m0 >= 192) {
                        // K -> packed 64B rows: kP[b][head][tok][32], cols 24..31 zeroed
                        int head = (m0 - 192) / 24 + half;
                        unsigned short* dst = Ck + ((size_t)(bI * 8 + head) * NTOK + n0h + row) * KST;
                        #pragma unroll
                        for (int u = 0; u < 3; ++u)
                            *(u16x8*)&dst[u * 8] = *(const u16x8*)&src[u * 8];
                        *(u16x8*)&dst[24] = (u16x8)0;
                    } else {
                        unsigned short* dst = Ct + ((size_t)bI * NTOK + n0h + row) * QST + m0 + half * 24;
                        #pragma unroll
                        for (int u = 0; u < 3; ++u)
                            *(u16x8*)&dst[u * 8] = *(const u16x8*)&src[u * 8];
                    }
                }
            } else {
                for (int u = tid; u < 48 * 8; u += 256) {
                    int row = u >> 3, seg = u & 7;
                    unsigned short* dst = Cv + ((size_t)bI * EE + (m0 - 384) + row) * NTOK + n0h + seg * 8;
                    *(u16x8*)dst = *(const u16x8*)&Ts[row * 72 + seg * 8];
                }
            }
        }
    }
}

// ---------------- MFMA bf16 attention: 2-wave blocks, dbuf Vs, bare v_exp + setprio (frozen) ----------------
__global__ __launch_bounds__(128) void attn_k2(const unsigned short* __restrict__ qT,
                                               const unsigned short* __restrict__ kP,
                                               const unsigned short* __restrict__ vF,
                                               unsigned short* __restrict__ oT)
{
    __shared__ unsigned short Vs[2][32 * 136];    // [buf][d][tok pad 136]; rows 18..30 zero, 31 ones

    int blk = blockIdx.x;
    int bhs = blk & 127;                          // blocks sharing K/V are 128 apart -> same XCD
    int qc  = blk >> 7;                           // 16 chunks of 64 q
    int b = bhs >> 5, h = (bhs >> 2) & 7, s = bhs & 3;
    int tid  = threadIdx.x;
    int wv   = tid >> 6;                          // 0..1
    int lane = tid & 63;
    int l15 = lane & 15, l4 = lane >> 4;
    int q0 = qc * 64;
    int tokbase = s * 1024;

    // pad rows 18..31 of both buffers once (staging only rewrites rows 0..17)
    for (int v = tid; v < 14 * 16; v += 128) {
        int d = 18 + (v >> 4), seg = v & 15;
        unsigned short val = (d == 31) ? (unsigned short)0x3F80 : (unsigned short)0;
        u16x8 vv = (u16x8)val;
        *(u16x8*)&Vs[0][d * 136 + seg * 8] = vv;
        *(u16x8*)&Vs[1][d * 136 + seg * 8] = vv;
    }

    bf16x8 qf[2];                                 // B-frag: col=q(l15), k=d(l4*8+j)
    #pragma unroll
    for (int ni = 0; ni < 2; ++ni) {
        u16x8 raw = *(const u16x8*)(qT + ((size_t)b * NTOK + tokbase + q0 + wv * 32 + ni * 16 + l15) * QST
                                    + 24 * h + l4 * 8);
        if (l4 == 3) raw = (u16x8)0;
        qf[ni] = *(bf16x8*)&raw;
    }

    floatx4 oacc[2][2];                           // [ni][nd]; O^T rows d=nd*16+l4*4+r, col q
    #pragma unroll
    for (int ni = 0; ni < 2; ++ni)
        #pragma unroll
        for (int nd = 0; nd < 2; ++nd)
            oacc[ni][nd] = (floatx4){0.f, 0.f, 0.f, 0.f};

    // V staging: 288 16B-chunks per 128-tok round over 128 threads (chunks tid, tid+128, tid+256)
    const unsigned short* vbb = vF + (size_t)b * EE * NTOK + tokbase;
    int seg0 = tid & 15;
    int d0 = tid >> 4;                            // d 0..7
    int d1 = 8 + (tid >> 4);                      // d 8..15
    bool x2 = (tid < 32);
    int d2 = 16 + (tid >> 4);                     // d 16..17 (tid<32)
    const unsigned short* vsrc0 = vbb + (size_t)(h * 18 + d0) * NTOK + seg0 * 8;
    const unsigned short* vsrc1 = vbb + (size_t)(h * 18 + d1) * NTOK + seg0 * 8;
    const unsigned short* vsrc2 = vbb + (size_t)(h * 18 + d2) * NTOK + seg0 * 8;

    // prologue: round 0 -> Vs[0]; preload round-1 V into regs
    {
        u16x8 v0 = *(const u16x8*)vsrc0;
        u16x8 v1 = *(const u16x8*)vsrc1;
        *(u16x8*)&Vs[0][d0 * 136 + seg0 * 8] = v0;
        *(u16x8*)&Vs[0][d1 * 136 + seg0 * 8] = v1;
        if (x2) {
            u16x8 v2 = *(const u16x8*)vsrc2;
            *(u16x8*)&Vs[0][d2 * 136 + seg0 * 8] = v2;
        }
    }
    u16x8 pv0 = *(const u16x8*)(vsrc0 + 128);
    u16x8 pv1 = *(const u16x8*)(vsrc1 + 128);
    u16x8 pv2;
    if (x2) pv2 = *(const u16x8*)(vsrc2 + 128);

    const unsigned short* kRow = kP + ((size_t)(b * 8 + h) * NTOK + tokbase + l15) * KST + l4 * 8;
    __syncthreads();

    for (int c0 = 0; c0 < 1024; c0 += 128) {
        const int cur = (c0 >> 7) & 1;
        int cn = c0 + 128;
        // write next round's V into the other buffer; start loading round r+2
        if (cn < 1024) {
            *(u16x8*)&Vs[cur ^ 1][d0 * 136 + seg0 * 8] = pv0;
            *(u16x8*)&Vs[cur ^ 1][d1 * 136 + seg0 * 8] = pv1;
            if (x2) *(u16x8*)&Vs[cur ^ 1][d2 * 136 + seg0 * 8] = pv2;
            int cn2 = c0 + 256;
            if (cn2 < 1024) {
                pv0 = *(const u16x8*)(vsrc0 + cn2);
                pv1 = *(const u16x8*)(vsrc1 + cn2);
                if (x2) pv2 = *(const u16x8*)(vsrc2 + cn2);
            }
        }

        // K for the whole round (compiler's vmcnt lets sub1's 4 loads fly under sub0 compute)
        bf16x8 kreg[8];
        #pragma unroll
        for (int i = 0; i < 8; ++i) {
            u16x8 raw = *(const u16x8*)(kRow + (unsigned)(c0 + i * 16) * KST);
            kreg[i] = *(bf16x8*)&raw;
        }

        #pragma unroll
        for (int sub = 0; sub < 2; ++sub) {
            unsigned int pk0[2][4], pk1[2][4];    // [ni][mi] — transient within sub
            #pragma unroll
            for (int ni = 0; ni < 2; ++ni) {
                floatx4 sacc[4];
                __builtin_amdgcn_s_setprio(1);
                #pragma unroll
                for (int mi = 0; mi < 4; ++mi) {
                    floatx4 z = (floatx4){0.f, 0.f, 0.f, 0.f};
                    sacc[mi] = __builtin_amdgcn_mfma_f32_16x16x32_bf16(kreg[sub * 4 + mi], qf[ni], z, 0, 0, 0);
                }
                __builtin_amdgcn_s_setprio(0);
                #pragma unroll
                for (int mi = 0; mi < 4; ++mi) {
                    pk0[ni][mi] = pack_bf_trunc(fexp2(sacc[mi][0]), fexp2(sacc[mi][1]));
                    pk1[ni][mi] = pack_bf_trunc(fexp2(sacc[mi][2]), fexp2(sacc[mi][3]));
                }
            }

            // PV: af read once per (c,nd), shared by both ni q-groups
            #pragma unroll
            for (int c = 0; c < 2; ++c) {
                union { unsigned int u[4]; bf16x8 v; } bfr[2];
                #pragma unroll
                for (int ni = 0; ni < 2; ++ni) {
                    unsigned int B0 = pk0[ni][2 * c], B2 = pk0[ni][2 * c + 1];
                    unsigned int B1 = pk1[ni][2 * c], B3 = pk1[ni][2 * c + 1];
                    plswap32(B0, B2); plswap16(B0, B2);
                    plswap32(B1, B3); plswap16(B1, B3);
                    bfr[ni].u[0] = B0; bfr[ni].u[1] = B1; bfr[ni].u[2] = B2; bfr[ni].u[3] = B3;
                }
                __builtin_amdgcn_s_setprio(1);
                #pragma unroll
                for (int nd = 0; nd < 2; ++nd) {
                    bf16x8 af = *(const bf16x8*)&Vs[cur][(nd * 16 + l15) * 136 + sub * 64 + c * 32 + l4 * 8];
                    #pragma unroll
                    for (int ni = 0; ni < 2; ++ni)
                        oacc[ni][nd] = __builtin_amdgcn_mfma_f32_16x16x32_bf16(af, bfr[ni].v,
                                                                               oacc[ni][nd], 0, 0, 0);
                }
                __builtin_amdgcn_s_setprio(0);
            }
        }

        __syncthreads();                          // reads of Vs[cur] done; next round may overwrite
    }

    // row-sum sits at d=31 (ones row of Vs): oacc[ni][1][3] on lanes l4=3, col=q=l15
    #pragma unroll
    for (int ni = 0; ni < 2; ++ni) {
        float lsum = __shfl(oacc[ni][1][3], 48 + l15, 64);
        float inv  = 1.f / lsum;
        size_t rowi = (size_t)b * NTOK + tokbase + q0 + wv * 32 + ni * 16 + l15;
        unsigned short* orow = oT + rowi * 160 + h * 18;
        unsigned int w0 = (unsigned)f2bf(oacc[ni][0][0] * inv) | ((unsigned)f2bf(oacc[ni][0][1] * inv) << 16);
        unsigned int w1 = (unsigned)f2bf(oacc[ni][0][2] * inv) | ((unsigned)f2bf(oacc[ni][0][3] * inv) << 16);
        *(unsigned int*)&orow[l4 * 4]     = w0;   // d = 4*l4 + 0,1
        *(unsigned int*)&orow[l4 * 4 + 2] = w1;   // d = 4*l4 + 2,3
        if (l4 == 0) {                            // d = 16,17
            unsigned int w2 = (unsigned)f2bf(oacc[ni][1][0] * inv) | ((unsigned)f2bf(oacc[ni][1][1] * inv) << 16);
            *(unsigned int*)&orow[16] = w2;
        }
        if (h == 7 && l4 < 2) {                   // zero pad cols 144..159
            u16x8 z = (u16x8)0;
            *(u16x8*)(oT + rowi * 160 + 144 + l4 * 8) = z;
        }
    }
}

// ---------------- fold (bf16 cols) + masked residual, 8-pixel vectorized threads ----------------
__global__ __launch_bounds__(256) void fold_k(const unsigned short* __restrict__ cols,
                                              const float* __restrict__ tprev,
                                              float* __restrict__ t)
{
    int base = blockIdx.x * 2048 + threadIdx.x * 8;   // 8 consecutive w pixels
    int w0 = base & 63;                               // multiple of 8
    int h  = (base >> 6) & 63;
    int c  = (base >> 12) & 31;
    int b  = base >> 17;
    const unsigned short* cb = cols + (size_t)b * DD * NTOK + (size_t)c * 9 * NTOK;
    float sum[8];
    #pragma unroll
    for (int p = 0; p < 8; ++p) sum[p] = 0.f;

    #pragma unroll
    for (int i = 0; i < 3; ++i) {
        int hs = h + 1 - i;
        if ((unsigned)hs < 64u) {
            #pragma unroll
            for (int j = 0; j < 3; ++j) {
                const unsigned short* row = cb + (size_t)(i * 3 + j) * NTOK + hs * 64;
                u16x8 mid = *(const u16x8*)&row[w0];          // w0..w0+7
                if (j == 1) {
                    #pragma unroll
                    for (int p = 0; p < 8; ++p) sum[p] += bf2f(mid[p]);
                } else if (j == 0) {                          // ws = w+1
                    #pragma unroll
                    for (int p = 0; p < 7; ++p) sum[p] += bf2f(mid[p + 1]);
                    if (w0 < 56) sum[7] += bf2f(row[w0 + 8]); // w0==56 -> px7 ws=64 masked
                } else {                                      // j==2: ws = w-1
                    if (w0 > 0) sum[0] += bf2f(row[w0 - 1]);  // w0==0 -> px0 ws=-1 masked
                    #pragma unroll
                    for (int p = 1; p < 8; ++p) sum[p] += bf2f(mid[p - 1]);
                }
            }
        }
    }
    int ch = (h == 0 || h == 63) ? 2 : 3;
    const float* tp = tprev + base;
    float out[8];
    #pragma unroll
    for (int p = 0; p < 8; ++p) {
        int wp = w0 + p;
        int cw_ = (wp == 0 || wp == 63) ? 2 : 3;
        out[p] = sum[p] + (float)(ch * cw_) * tp[p];
    }
    *(float4*)&t[base]     = *(const float4*)&out[0];
    *(float4*)&t[base + 4] = *(const float4*)&out[4];
}

// ---------------- conv3x3 + ELU + residual, 4-pixel register strips ----------------
__global__ __launch_bounds__(256) void conv_k(const float* __restrict__ t,
    const float* __restrict__ cw, const float* __restrict__ cbias,
    const float* __restrict__ x, float* __restrict__ out)
{
    __shared__ float wsh[CC * 9];
    int blk = blockIdx.x;
    int band = blk & 3, co = (blk >> 2) & 31, b = blk >> 7;
    int tid = threadIdx.x;
    for (int u = tid; u < CC * 9; u += 256) wsh[u] = cw[co * CC * 9 + u];
    __syncthreads();
    int h = band * 16 + (tid >> 4);
    int w0 = (tid & 15) << 2;
    const float* tb = t + (size_t)b * CC * 4096;
    float bias = cbias[co];
    float a0 = bias, a1 = bias, a2 = bias, a3 = bias;
    for (int ci = 0; ci < CC; ++ci) {
        const float* tc = tb + (size_t)ci * 4096;
        const float* wr = &wsh[ci * 9];
        #pragma unroll
        for (int i = 0; i < 3; ++i) {
            int hr = h + i - 1;
            if ((unsigned)hr < 64u) {
                const float* row = tc + hr * 64;
                float vl = (w0 > 0)  ? row[w0 - 1] : 0.f;
                float4 c4 = *(const float4*)&row[w0];
                float vr = (w0 < 60) ? row[w0 + 4] : 0.f;
                float wj0 = wr[i * 3], wj1 = wr[i * 3 + 1], wj2 = wr[i * 3 + 2];
                a0 = fmaf(wj0, vl,   a0); a0 = fmaf(wj1, c4.x, a0); a0 = fmaf(wj2, c4.y, a0);
                a1 = fmaf(wj0, c4.x, a1); a1 = fmaf(wj1, c4.y, a1); a1 = fmaf(wj2, c4.z, a1);
                a2 = fmaf(wj0, c4.y, a2); a2 = fmaf(wj1, c4.z, a2); a2 = fmaf(wj2, c4.w, a2);
                a3 = fmaf(wj0, c4.z, a3); a3 = fmaf(wj1, c4.w, a3); a3 = fmaf(wj2, vr,   a3);
            }
        }
    }
    size_t oidx = ((size_t)(b * CC + co) * 4096) + h * 64 + w0;
    float4 xin = *(const float4*)&x[oidx];
    float4 o;
    o.x = xin.x + ((a0 > 0.f) ? a0 : (__expf(a0) - 1.f));
    o.y = xin.y + ((a1 > 0.f) ? a1 : (__expf(a1) - 1.f));
    o.z = xin.z + ((a2 > 0.f) ? a2 : (__expf(a2) - 1.f));
    o.w = xin.w + ((a3 > 0.f) ? a3 : (__expf(a3) - 1.f));
    *(float4*)&out[oidx] = o;
}

extern "C" void kernel_launch(void* const* d_in, const int* in_sizes, int n_in,
                              void* d_out, int out_size, void* d_ws, size_t ws_size,
                              hipStream_t stream)
{
    const float* x    = (const float*)d_in[0];
    const float* ln_g = (const float*)d_in[1];
    const float* ln_b = (const float*)d_in[2];
    const float* cw   = (const float*)d_in[3];
    const float* cb   = (const float*)d_in[4];
    const float* wr[3]   = {(const float*)d_in[5],  (const float*)d_in[10], (const float*)d_in[15]};
    const float* br[3]   = {(const float*)d_in[6],  (const float*)d_in[11], (const float*)d_in[16]};
    const float* wqkv[3] = {(const float*)d_in[7],  (const float*)d_in[12], (const float*)d_in[17]};
    const float* we[3]   = {(const float*)d_in[8],  (const float*)d_in[13], (const float*)d_in[18]};
    const float* be[3]   = {(const float*)d_in[9],  (const float*)d_in[14], (const float*)d_in[19]};
    float* out = (float*)d_out;

    char* p = (char*)d_ws;
    unsigned short* cols_bf = (unsigned short*)p; p += (size_t)BN * DD * NTOK * 2; // 9.4 MB (emha out, bf16)
    unsigned short* oT    = (unsigned short*)p; p += (size_t)BN * NTOK * 288 * 2;  // 9.4 MB (attn out, 160-stride)
    unsigned short* xrT   = (unsigned short*)p; p += (size_t)BN * NTOK * 160 * 2;  // 5.2 MB
    unsigned short* qT    = (unsigned short*)p; p += (size_t)BN * NTOK * QST * 2;  // 6.3 MB (Q only)
    unsigned short* kP    = (unsigned short*)p; p += (size_t)BN * 8 * NTOK * KST * 2; // 8.4 MB (packed K, 64B rows; MUST follow qT: qf tail overread)
    unsigned short* vF    = (unsigned short*)p; p += (size_t)BN * EE * NTOK * 2;   // 4.7 MB
    float* tA   = (float*)p;              p += (size_t)BN * CC * HH * WW * 4;
    float* tB   = (float*)p;              p += (size_t)BN * CC * HH * WW * 4;
    unsigned short* wg_bf   = (unsigned short*)p; p += (size_t)3 * EE * DD * 2;
    unsigned short* wqkv_bf = (unsigned short*)p; p += (size_t)3 * MQKV * 160 * 2;
    unsigned short* we_bf   = (unsigned short*)p; p += (size_t)3 * DD * 160 * 2;
    float* wgsum = (float*)p;             p += 3 * EE * 4;
    float* wbeta = (float*)p;             p += 3 * EE * 4;
    (void)in_sizes; (void)n_in; (void)out_size; (void)ws_size;

    setup_k<<<1533, 256, 0, stream>>>(wr[0], br[0], wr[1], br[1], wr[2], br[2], ln_g, ln_b,
                                      wqkv[0], wqkv[1], wqkv[2], we[0], we[1], we[2],
                                      wg_bf, wgsum, wbeta, wqkv_bf, we_bf);

    const float* tin = x;
    float* touts[3] = {tA, tB, tA};
    for (int l = 0; l < 3; ++l) {
        // fused unfold + LN + gemm1
        fgemm1_k<<<256, 512, 0, stream>>>(tin, wg_bf + (size_t)l * EE * DD,
                                          wgsum + l * EE, wbeta + l * EE, xrT);
        // gemm2: K=160, M=528 (NYB=11), NT=128 -> grid 1408
        mgemm_k<160, 0, 11><<<1408, 256, 0, stream>>>(
            wqkv_bf + (size_t)l * MQKV * 160, xrT, 160, qT, vF, kP, nullptr);
        attn_k2<<<2048, 128, 0, stream>>>(qT, kP, vF, oT);
        // gemm3: K=160, M=288 (NYB=6), NT=128 -> grid 768
        mgemm_k<160, 2, 6><<<768, 256, 0, stream>>>(
            we_bf + (size_t)l * DD * 160, oT, 160, cols_bf, nullptr, nullptr, be[l]);
        fold_k<<<256, 256, 0, stream>>>(cols_bf, tin, touts[l]);
        tin = touts[l];
    }
    conv_k<<<512, 256, 0, stream>>>(tA, cw, cb, x, out);
}